// Round 4
// baseline (71.705 us; speedup 1.0000x reference)
//
#include <hip/hip_runtime.h>
#include <hip/hip_bf16.h>
#include <stdint.h>

// PUMA functional model == exact integer GEMM. Proof sketch:
//  - analog = sum_{128 rows} bit{0,1}*slice{0..3} <= 384 < 511 = 2^ADC_BIT-1,
//    integers exact in f32, so the ADC round/clip is the identity.
//  - slice shift-add reassembles wint = clip(rne(|w|*4096),0,65535)  (u16)
//  - stream shift-add reassembles xi = clip(rne(x*4096),-32768,32767) (s16)
//  => per polarity p = sum_i xi*w, |p| < 2^41 (exact int64), then
//     q(v) = clamp(rne(v/4096),-32768,32767)*2^-12 per polarity,
//     out = q(p) - q(n) + bias (f32).
//
// Exactness without data assumptions: w split into u8 limbs (wl, wh).
//  |xi|<=2^15, limb<=255 -> |term| <= 8.36e6; a 64-term chunk <= 5.35e8 < 2^31,
//  so int32 (and v_dot2_i32_i16) accumulation per chunk is exact; widen to
//  int64 per chunk, reduce chunks in LDS.
//
// ws: [0,4MB)    packedW u32 [i][o]  (pl | ph<<8 | nl<<16 | nh<<24)
//     [4MB,+128K) xq u32 [b/4][ipair][b%4] = x(b,2p) | x(b,2p+1)<<16  (s16 pair)

#define WS_XQ_OFF (4u * 1024u * 1024u)

typedef short short2v __attribute__((ext_vector_type(2)));

__device__ __forceinline__ uint32_t packw(float w) {
    float p = __builtin_rintf(fmaxf(w, 0.0f) * 4096.0f);
    float n = __builtin_rintf(fmaxf(-w, 0.0f) * 4096.0f);
    p = fminf(p, 65535.0f);
    n = fminf(n, 65535.0f);
    return (uint32_t)p | ((uint32_t)n << 16);   // bytes: pl, ph, nl, nh
}

__device__ __forceinline__ int qx(float v) {
    float q = __builtin_rintf(v * 4096.0f);
    return (int)fminf(fmaxf(q, -32768.0f), 32767.0f);
}

// Blocks 0..255: one 64(o) x 64(i) weight tile -> packedW[i][o].
// Blocks 256..271: quantize 4 rows of x -> s16-pair layout xq[btile][pair][b].
__global__ __launch_bounds__(256) void quant_kernel(
        const float* __restrict__ w, const float* __restrict__ x,
        uint32_t* __restrict__ packedW, uint32_t* __restrict__ xq) {
    const int bid = blockIdx.x;
    const int tid = threadIdx.x;
    if (bid < 256) {
        __shared__ uint32_t lds[64][69];   // [o][i]; read banks (5*o+i)%32
        const int to = (bid >> 4) * 64;    // o tile base
        const int ti = (bid & 15) * 64;    // i tile base
        const int r = tid >> 4;            // 0..15
        const int c = (tid & 15) * 4;      // 0..60
        #pragma unroll
        for (int it = 0; it < 4; ++it) {
            const int ol = r + it * 16;
            const float4 wv = *(const float4*)(w + (size_t)(to + ol) * 1024 + ti + c);
            lds[ol][c + 0] = packw(wv.x);
            lds[ol][c + 1] = packw(wv.y);
            lds[ol][c + 2] = packw(wv.z);
            lds[ol][c + 3] = packw(wv.w);
        }
        __syncthreads();
        const int ol = tid & 63;           // lane -> o (coalesced global write)
        const int wq = tid >> 6;           // wave quarter 0..3
        #pragma unroll
        for (int it = 0; it < 16; ++it) {
            const int il = wq + it * 4;
            packedW[(size_t)(ti + il) * 1024 + to + ol] = lds[ol][il];
        }
    } else {
        const int xb = bid - 256;          // b-tile 0..15 (rows 4xb..4xb+3)
        uint32_t* __restrict__ dst = xq + xb * 2048;   // [512 pair][4 b]
        #pragma unroll
        for (int pp = 0; pp < 2; ++pp) {
            const int p = pp * 256 + tid;  // pair index 0..511
            uint32_t v0, v1, v2, v3;
            {
                const float2 a = *(const float2*)(x + (size_t)(xb * 4 + 0) * 1024 + p * 2);
                v0 = ((uint32_t)qx(a.x) & 0xFFFFu) | ((uint32_t)qx(a.y) << 16);
            }
            {
                const float2 a = *(const float2*)(x + (size_t)(xb * 4 + 1) * 1024 + p * 2);
                v1 = ((uint32_t)qx(a.x) & 0xFFFFu) | ((uint32_t)qx(a.y) << 16);
            }
            {
                const float2 a = *(const float2*)(x + (size_t)(xb * 4 + 2) * 1024 + p * 2);
                v2 = ((uint32_t)qx(a.x) & 0xFFFFu) | ((uint32_t)qx(a.y) << 16);
            }
            {
                const float2 a = *(const float2*)(x + (size_t)(xb * 4 + 3) * 1024 + p * 2);
                v3 = ((uint32_t)qx(a.x) & 0xFFFFu) | ((uint32_t)qx(a.y) << 16);
            }
            *(uint4*)(dst + p * 4) = make_uint4(v0, v1, v2, v3);
        }
    }
}

// Grid 256 = 16 o-tiles x 16 b-tiles; block 1024 thr = 64 o-lanes x 16 K-chunks
// of 64 i (32 pairs). Per pair: 2 coalesced W dwords + 1 broadcast ds_read_b128
// + 4 byte-pair merges + 16 v_dot2_i32_i16 (= 32 limb-MACs).
// o_t = bid & 15 -> all b-tiles sharing a W slice land on one XCD (L2 reuse).
__global__ __launch_bounds__(1024) void mvm_kernel(
        const uint32_t* __restrict__ packedW, const uint32_t* __restrict__ xq,
        const float* __restrict__ bias, float* __restrict__ out) {
    __shared__ int xs[2048];               // [pair][b] s16 pairs, 8 KB
    __shared__ long long red[8][8][64];    // [b*2+pol][chunk-half][o_l], 32 KB

    const int tid = threadIdx.x;
    const int bid = blockIdx.x;
    const int o_t = bid & 15;
    const int b_t = bid >> 4;
    const int o_l = tid & 63;
    const int c = tid >> 6;                // K-chunk 0..15
    const int o = o_t * 64 + o_l;

    if (tid < 512)
        *(int4*)(xs + tid * 4) = *(const int4*)(xq + (size_t)b_t * 2048 + tid * 4);
    __syncthreads();

    const uint32_t* __restrict__ wp = packedW + (size_t)(c * 64) * 1024 + o;
    const int* __restrict__ xp = xs + c * 128;       // 32 pairs * 4 b

    int apl[4] = {0, 0, 0, 0}, aph[4] = {0, 0, 0, 0};
    int anl[4] = {0, 0, 0, 0}, anh[4] = {0, 0, 0, 0};

    #pragma unroll 4
    for (int p = 0; p < 32; ++p) {
        const uint32_t wv0 = wp[(p * 2 + 0) * 1024];
        const uint32_t wv1 = wp[(p * 2 + 1) * 1024];
        // limb pairs: lo16 = even i (wv0), hi16 = odd i (wv1)
        const uint32_t wPL = (wv0 & 0xFFu)          | ((wv1 & 0xFFu) << 16);
        const uint32_t wPH = ((wv0 >> 8) & 0xFFu)   | (((wv1 >> 8) & 0xFFu) << 16);
        const uint32_t wNL = ((wv0 >> 16) & 0xFFu)  | (((wv1 >> 16) & 0xFFu) << 16);
        const uint32_t wNH = (wv0 >> 24)            | ((wv1 >> 24) << 16);
        const int4 xv = *(const int4*)(xp + p * 4);  // broadcast (wave-uniform)
#if __has_builtin(__builtin_amdgcn_sdot2)
        const short2v sPL = __builtin_bit_cast(short2v, wPL);
        const short2v sPH = __builtin_bit_cast(short2v, wPH);
        const short2v sNL = __builtin_bit_cast(short2v, wNL);
        const short2v sNH = __builtin_bit_cast(short2v, wNH);
        {
            const short2v xa = __builtin_bit_cast(short2v, xv.x);
            apl[0] = __builtin_amdgcn_sdot2(xa, sPL, apl[0], false);
            aph[0] = __builtin_amdgcn_sdot2(xa, sPH, aph[0], false);
            anl[0] = __builtin_amdgcn_sdot2(xa, sNL, anl[0], false);
            anh[0] = __builtin_amdgcn_sdot2(xa, sNH, anh[0], false);
        }
        {
            const short2v xa = __builtin_bit_cast(short2v, xv.y);
            apl[1] = __builtin_amdgcn_sdot2(xa, sPL, apl[1], false);
            aph[1] = __builtin_amdgcn_sdot2(xa, sPH, aph[1], false);
            anl[1] = __builtin_amdgcn_sdot2(xa, sNL, anl[1], false);
            anh[1] = __builtin_amdgcn_sdot2(xa, sNH, anh[1], false);
        }
        {
            const short2v xa = __builtin_bit_cast(short2v, xv.z);
            apl[2] = __builtin_amdgcn_sdot2(xa, sPL, apl[2], false);
            aph[2] = __builtin_amdgcn_sdot2(xa, sPH, aph[2], false);
            anl[2] = __builtin_amdgcn_sdot2(xa, sNL, anl[2], false);
            anh[2] = __builtin_amdgcn_sdot2(xa, sNH, anh[2], false);
        }
        {
            const short2v xa = __builtin_bit_cast(short2v, xv.w);
            apl[3] = __builtin_amdgcn_sdot2(xa, sPL, apl[3], false);
            aph[3] = __builtin_amdgcn_sdot2(xa, sPH, aph[3], false);
            anl[3] = __builtin_amdgcn_sdot2(xa, sNL, anl[3], false);
            anh[3] = __builtin_amdgcn_sdot2(xa, sNH, anh[3], false);
        }
#else
        // fallback: explicit mul24 limb MACs (exact, i24 operands)
        const int pl0 = (int)(wv0 & 255u), pl1 = (int)(wv1 & 255u);
        const int ph0 = (int)((wv0 >> 8) & 255u), ph1 = (int)((wv1 >> 8) & 255u);
        const int nl0 = (int)((wv0 >> 16) & 255u), nl1 = (int)((wv1 >> 16) & 255u);
        const int nh0 = (int)(wv0 >> 24), nh1 = (int)(wv1 >> 24);
        {
            const int xe = (int)(short)(xv.x & 0xFFFF), xo = xv.x >> 16;
            apl[0] += __mul24(xe, pl0) + __mul24(xo, pl1);
            aph[0] += __mul24(xe, ph0) + __mul24(xo, ph1);
            anl[0] += __mul24(xe, nl0) + __mul24(xo, nl1);
            anh[0] += __mul24(xe, nh0) + __mul24(xo, nh1);
        }
        {
            const int xe = (int)(short)(xv.y & 0xFFFF), xo = xv.y >> 16;
            apl[1] += __mul24(xe, pl0) + __mul24(xo, pl1);
            aph[1] += __mul24(xe, ph0) + __mul24(xo, ph1);
            anl[1] += __mul24(xe, nl0) + __mul24(xo, nl1);
            anh[1] += __mul24(xe, nh0) + __mul24(xo, nh1);
        }
        {
            const int xe = (int)(short)(xv.z & 0xFFFF), xo = xv.z >> 16;
            apl[2] += __mul24(xe, pl0) + __mul24(xo, pl1);
            aph[2] += __mul24(xe, ph0) + __mul24(xo, ph1);
            anl[2] += __mul24(xe, nl0) + __mul24(xo, nl1);
            anh[2] += __mul24(xe, nh0) + __mul24(xo, nh1);
        }
        {
            const int xe = (int)(short)(xv.w & 0xFFFF), xo = xv.w >> 16;
            apl[3] += __mul24(xe, pl0) + __mul24(xo, pl1);
            aph[3] += __mul24(xe, ph0) + __mul24(xo, ph1);
            anl[3] += __mul24(xe, nl0) + __mul24(xo, nl1);
            anh[3] += __mul24(xe, nh0) + __mul24(xo, nh1);
        }
#endif
    }

    long long pp[4], pn[4];
    #pragma unroll
    for (int b = 0; b < 4; ++b) {
        pp[b] = (long long)apl[b] + ((long long)aph[b] << 8);
        pn[b] = (long long)anl[b] + ((long long)anh[b] << 8);
    }

    // two-phase chunk reduction: upper chunks write, lower chunks add
    if (c >= 8) {
        #pragma unroll
        for (int b = 0; b < 4; ++b) {
            red[b * 2 + 0][c - 8][o_l] = pp[b];
            red[b * 2 + 1][c - 8][o_l] = pn[b];
        }
    }
    __syncthreads();
    if (c < 8) {
        #pragma unroll
        for (int b = 0; b < 4; ++b) {
            red[b * 2 + 0][c][o_l] += pp[b];
            red[b * 2 + 1][c][o_l] += pn[b];
        }
    }
    __syncthreads();

    if (tid < 256) {
        const int ro = tid & 63;
        const int rb = tid >> 6;           // batch within tile
        long long ap = 0, an = 0;
        #pragma unroll
        for (int cc = 0; cc < 8; ++cc) {
            ap += red[rb * 2 + 0][cc][ro];
            an += red[rb * 2 + 1][cc][ro];
        }
        // ACM fixed-point quantization, per polarity, rne (exact in f64)
        double qp = rint((double)ap * (1.0 / 4096.0));
        qp = fmin(fmax(qp, -32768.0), 32767.0);
        double qn = rint((double)an * (1.0 / 4096.0));
        qn = fmin(fmax(qn, -32768.0), 32767.0);
        const int oo = o_t * 64 + ro;
        out[(size_t)(b_t * 4 + rb) * 1024 + oo] =
            (float)((qp - qn) * (1.0 / 4096.0)) + bias[oo];
    }
}

extern "C" void kernel_launch(void* const* d_in, const int* in_sizes, int n_in,
                              void* d_out, int out_size, void* d_ws, size_t ws_size,
                              hipStream_t stream) {
    const float* x    = (const float*)d_in[0];   // [64,1024]
    const float* w    = (const float*)d_in[1];   // [1024,1024]
    const float* bias = (const float*)d_in[2];   // [1024]
    float* out = (float*)d_out;                  // [64,1024]

    uint32_t* packedW = (uint32_t*)d_ws;
    uint32_t* xq = (uint32_t*)((char*)d_ws + WS_XQ_OFF);

    quant_kernel<<<272, 256, 0, stream>>>(w, x, packedW, xq);
    mvm_kernel<<<256, 1024, 0, stream>>>(packedW, xq, bias, out);
}